// Round 16
// baseline (136.297 us; speedup 1.0000x reference)
//
#include <hip/hip_runtime.h>

typedef __attribute__((ext_vector_type(4))) float f32x4;
typedef __attribute__((ext_vector_type(8))) short bf16x8;
typedef __attribute__((ext_vector_type(2))) unsigned int u32x2;
typedef __attribute__((ext_vector_type(4))) unsigned int u32x4;

#define EPSV 1e-5f

// workspace layout (bytes)
#define OFF_BUFA 0u
#define OFF_BUFB 33554432u
#define OFF_T    67108864u
#define OFF_WQ1  (OFF_T + 0u)       // f32 [128][12]  (9 taps used)
#define OFF_R3F  (OFF_T + 6144u)    // f32 [9][128]   integer-valued
#define OFF_CST3 (OFF_T + 10752u)   // f32x4 [128]
#define OFF_CST1 (OFF_T + 12800u)   // f32x4 [128]
#define OFF_R2BF (OFF_T + 14848u)   // bf16 [128][128]
#define OFF_CST2 (OFF_T + 47616u)   // f32x4 [128]
#define OFF_R4BF (OFF_T + 49664u)   // bf16 [128][128]
#define OFF_CST4 (OFF_T + 82432u)   // f32x4 [128]
#define OFF_R5BF (OFF_T + 84480u)   // bf16 [32][128] (rows 19..31 zero)
#define OFF_CST5 (OFF_T + 92672u)   // float2 [32]

struct PArgs {
  const float *dw1, *pw1, *dw2, *pw2, *clsw, *clsb;
  const float *g1, *b1, *m1, *v1;
  const float *g2, *b2, *m2, *v2;
  const float *g3, *b3, *m3, *v3;
  const float *g4, *b4, *m4, *v4;
  const float *s1, *s2, *s3, *s4;
};

__device__ __forceinline__ unsigned short f2bf(float f) {
  return (unsigned short)(__builtin_bit_cast(unsigned int, f) >> 16);
}
__device__ __forceinline__ float clip7(float r) { return fminf(fmaxf(r, -7.f), 7.f); }

// BN-transformed value; expression identical to all previous rounds.
__device__ __forceinline__ float bnval(float a, f32x4 c) {
  return (a * c.x - c.z) * c.y + c.w;
}

// Quantize 4 values: fast path u = t*(1/s) + rint; if any lane lands within
// 3e-5 of a half-integer (fast-path abs error <= ~4e-6 for |u|<=16), the wave
// recomputes with exact division -> emitted k bit-identical to exact path.
__device__ __forceinline__ void qstep4(float t0, float t1, float t2, float t3,
                                       float s, float rs,
                                       float &k0, float &k1, float &k2, float &k3) {
  float u0 = t0 * rs, u1 = t1 * rs, u2 = t2 * rs, u3 = t3 * rs;
  float f0 = rintf(u0), f1 = rintf(u1), f2 = rintf(u2), f3 = rintf(u3);
  float d0 = fabsf(fabsf(u0 - f0) - 0.5f);
  float d1 = fabsf(fabsf(u1 - f1) - 0.5f);
  float d2 = fabsf(fabsf(u2 - f2) - 0.5f);
  float d3 = fabsf(fabsf(u3 - f3) - 0.5f);
  bool near = (d0 < 3e-5f) | (d1 < 3e-5f) | (d2 < 3e-5f) | (d3 < 3e-5f);
  if (__any(near)) {
    f0 = rintf(t0 / s); f1 = rintf(t1 / s);
    f2 = rintf(t2 / s); f3 = rintf(t3 / s);
  }
  k0 = fminf(fmaxf(f0, 0.f), 15.f);
  k1 = fminf(fmaxf(f1, 0.f), 15.f);
  k2 = fminf(fmaxf(f2, 0.f), 15.f);
  k3 = fminf(fmaxf(f3, 0.f), 15.f);
}

// 4 u8 -> 2 dwords of packed bf16
__device__ __forceinline__ void cvt2(unsigned int d, unsigned int &lo, unsigned int &hi) {
  float f0 = (float)(d & 0xffu);
  float f1 = (float)((d >> 8) & 0xffu);
  float f2 = (float)((d >> 16) & 0xffu);
  float f3 = (float)(d >> 24);
  lo = (__builtin_bit_cast(unsigned int, f0) >> 16) | (__builtin_bit_cast(unsigned int, f1) & 0xffff0000u);
  hi = (__builtin_bit_cast(unsigned int, f2) >> 16) | (__builtin_bit_cast(unsigned int, f3) & 0xffff0000u);
}

__device__ __forceinline__ float wmax16(float v) {
  #pragma unroll
  for (int s = 1; s < 16; s <<= 1) v = fmaxf(v, __shfl_xor(v, s));
  return v;
}
__device__ __forceinline__ float wmax64(float v) {
  #pragma unroll
  for (int s = 1; s < 64; s <<= 1) v = fmaxf(v, __shfl_xor(v, s));
  return v;
}

// ---------------- prep: quantize weights, fold BN constants ----------------
__global__ __launch_bounds__(64) void prep_kernel(PArgs P, char* __restrict__ ws) {
  int bi = blockIdx.x, l = threadIdx.x;
  float* wq1 = (float*)(ws + OFF_WQ1);
  float* r3f = (float*)(ws + OFF_R3F);
  f32x4* cst1 = (f32x4*)(ws + OFF_CST1);
  f32x4* cst2 = (f32x4*)(ws + OFF_CST2);
  f32x4* cst3 = (f32x4*)(ws + OFF_CST3);
  f32x4* cst4 = (f32x4*)(ws + OFF_CST4);
  unsigned short* r2 = (unsigned short*)(ws + OFF_R2BF);
  unsigned short* r4 = (unsigned short*)(ws + OFF_R4BF);
  unsigned short* r5 = (unsigned short*)(ws + OFF_R5BF);
  float2* cst5 = (float2*)(ws + OFF_CST5);

  if (bi < 128) {
    int c = bi;
    float w = (l < 9) ? P.dw1[c * 9 + l] : 0.f;
    float mx = wmax16(fabsf(w));
    float sq = fmaxf(mx / 7.0f, 1e-8f);
    if (l < 9) wq1[c * 12 + l] = clip7(rintf(w / sq)) * sq;
    if (l == 0) {
      float sc = P.g1[c] / sqrtf(P.v1[c] + EPSV);
      cst1[c] = f32x4{1.f, sc, P.m1[c], P.b1[c]};
    }
  } else if (bi < 256) {
    int o = bi - 128;
    float w0 = P.pw1[o * 128 + l], w1 = P.pw1[o * 128 + 64 + l];
    float mx = wmax64(fmaxf(fabsf(w0), fabsf(w1)));
    float sq = fmaxf(mx / 7.0f, 1e-8f);
    r2[o * 128 + l]      = f2bf(clip7(rintf(w0 / sq)));
    r2[o * 128 + 64 + l] = f2bf(clip7(rintf(w1 / sq)));
    if (l == 0) {
      float sc = P.g2[o] / sqrtf(P.v2[o] + EPSV);
      cst2[o] = f32x4{P.s1[0] * sq, sc, P.m2[o], P.b2[o]};
    }
  } else if (bi < 384) {
    int c = bi - 256;
    float w = (l < 9) ? P.dw2[c * 9 + l] : 0.f;
    float mx = wmax16(fabsf(w));
    float sq = fmaxf(mx / 7.0f, 1e-8f);
    if (l < 9) r3f[l * 128 + c] = clip7(rintf(w / sq));
    if (l == 0) {
      float sc = P.g3[c] / sqrtf(P.v3[c] + EPSV);
      cst3[c] = f32x4{P.s2[0] * sq, sc, P.m3[c], P.b3[c]};
    }
  } else if (bi < 512) {
    int o = bi - 384;
    float w0 = P.pw2[o * 128 + l], w1 = P.pw2[o * 128 + 64 + l];
    float mx = wmax64(fmaxf(fabsf(w0), fabsf(w1)));
    float sq = fmaxf(mx / 7.0f, 1e-8f);
    r4[o * 128 + l]      = f2bf(clip7(rintf(w0 / sq)));
    r4[o * 128 + 64 + l] = f2bf(clip7(rintf(w1 / sq)));
    if (l == 0) {
      float sc = P.g4[o] / sqrtf(P.v4[o] + EPSV);
      cst4[o] = f32x4{P.s3[0] * sq, sc, P.m4[o], P.b4[o]};
    }
  } else {
    int o = bi - 512;
    if (o < 19) {
      float w0 = P.clsw[o * 128 + l], w1 = P.clsw[o * 128 + 64 + l];
      float mx = wmax64(fmaxf(fabsf(w0), fabsf(w1)));
      float sq = fmaxf(mx / 7.0f, 1e-8f);
      r5[o * 128 + l]      = f2bf(clip7(rintf(w0 / sq)));
      r5[o * 128 + 64 + l] = f2bf(clip7(rintf(w1 / sq)));
      if (l == 0) {
        float A5 = P.s4[0] * sq;
        float bq = rintf(P.clsb[o] / A5) * A5;
        cst5[o] = make_float2(A5, bq);
      }
    } else {
      r5[o * 128 + l] = 0; r5[o * 128 + 64 + l] = 0;
      if (l == 0) cst5[o] = make_float2(0.f, 0.f);
    }
  }
}

// ---------------- dw-conv1 phase A: per-plane streaming, rolling 3-row window ----------------
__global__ __launch_bounds__(512) void dwA_kernel(const float* __restrict__ x,
                                                  char* __restrict__ ws,
                                                  const float* __restrict__ s1p) {
  int bid = blockIdx.x;
  int b = bid & 7, c = bid >> 3;              // XCD x owns image b=x
  int tid = threadIdx.x;
  int wq = tid & 63, wv = tid >> 6;
  int w0 = wq << 2;
  int h0 = wv << 4;
  const float* wp = (const float*)(ws + OFF_WQ1) + c * 12;
  float k0 = wp[0], k1 = wp[1], k2 = wp[2], k3 = wp[3], k4 = wp[4],
        k5 = wp[5], k6 = wp[6], k7 = wp[7], k8 = wp[8];
  f32x4 cs = ((const f32x4*)(ws + OFF_CST1))[c];
  float s_act = *s1p;
  float rs = 1.0f / s_act;
  const float* plane = x + (((size_t)((b << 7) | c)) << 15);
  unsigned char* oplane = (unsigned char*)(ws + OFF_BUFB) + (((size_t)((b << 7) | c)) << 15);

  f32x4 vm = {0.f, 0.f, 0.f, 0.f};
  if (h0 > 0) vm = *(const f32x4*)(plane + ((h0 - 1) << 8) + w0);
  f32x4 v0 = *(const f32x4*)(plane + (h0 << 8) + w0);
  f32x4 vp = *(const f32x4*)(plane + ((h0 + 1) << 8) + w0);
  float lm = __shfl_up(vm.w, 1), l0 = __shfl_up(v0.w, 1), lp = __shfl_up(vp.w, 1);
  float rm = __shfl_down(vm.x, 1), r0 = __shfl_down(v0.x, 1), rp = __shfl_down(vp.x, 1);
  if (wq == 0)  { lm = 0.f; l0 = 0.f; lp = 0.f; }
  if (wq == 63) { rm = 0.f; r0 = 0.f; rp = 0.f; }

  #pragma unroll 4
  for (int i = 0; i < 16; i++) {
    int h = h0 + i;
    float y0 = 0.f, y1 = 0.f, y2 = 0.f, y3 = 0.f;
    // row -1 (k0,k1,k2) then row 0 (k3,k4,k5) then row +1 (k6,k7,k8) — r1 order
    y0 = fmaf(lm,   k0, y0); y0 = fmaf(vm.x, k1, y0); y0 = fmaf(vm.y, k2, y0);
    y1 = fmaf(vm.x, k0, y1); y1 = fmaf(vm.y, k1, y1); y1 = fmaf(vm.z, k2, y1);
    y2 = fmaf(vm.y, k0, y2); y2 = fmaf(vm.z, k1, y2); y2 = fmaf(vm.w, k2, y2);
    y3 = fmaf(vm.z, k0, y3); y3 = fmaf(vm.w, k1, y3); y3 = fmaf(rm,   k2, y3);

    y0 = fmaf(l0,   k3, y0); y0 = fmaf(v0.x, k4, y0); y0 = fmaf(v0.y, k5, y0);
    y1 = fmaf(v0.x, k3, y1); y1 = fmaf(v0.y, k4, y1); y1 = fmaf(v0.z, k5, y1);
    y2 = fmaf(v0.y, k3, y2); y2 = fmaf(v0.z, k4, y2); y2 = fmaf(v0.w, k5, y2);
    y3 = fmaf(v0.z, k3, y3); y3 = fmaf(v0.w, k4, y3); y3 = fmaf(r0,   k5, y3);

    y0 = fmaf(lp,   k6, y0); y0 = fmaf(vp.x, k7, y0); y0 = fmaf(vp.y, k8, y0);
    y1 = fmaf(vp.x, k6, y1); y1 = fmaf(vp.y, k7, y1); y1 = fmaf(vp.z, k8, y1);
    y2 = fmaf(vp.y, k6, y2); y2 = fmaf(vp.z, k7, y2); y2 = fmaf(vp.w, k8, y2);
    y3 = fmaf(vp.z, k6, y3); y3 = fmaf(vp.w, k7, y3); y3 = fmaf(rp,   k8, y3);

    float q0, q1, q2, q3;
    qstep4(bnval(y0, cs), bnval(y1, cs), bnval(y2, cs), bnval(y3, cs),
           s_act, rs, q0, q1, q2, q3);
    unsigned int pk = (unsigned int)q0 | ((unsigned int)q1 << 8) |
                      ((unsigned int)q2 << 16) | ((unsigned int)q3 << 24);
    *(unsigned int*)(oplane + (h << 8) + w0) = pk;

    // shift window; load row h+2 for next iteration
    vm = v0; lm = l0; rm = r0;
    v0 = vp; l0 = lp; r0 = rp;
    f32x4 nv = {0.f, 0.f, 0.f, 0.f};
    if (i < 15 && h + 2 < 128) nv = *(const f32x4*)(plane + ((h + 2) << 8) + w0);
    vp = nv;
    float nl = __shfl_up(nv.w, 1), nr = __shfl_down(nv.x, 1);
    if (wq == 0)  nl = 0.f;
    if (wq == 63) nr = 0.f;
    lp = nl; rp = nr;
  }
}

// ---------------- pw1 from NCHW: staging does the transpose in-register ----------------
__global__ __launch_bounds__(256) void pwn_kernel(const unsigned char* __restrict__ in,
                                                  unsigned char* __restrict__ out,
                                                  const unsigned short* __restrict__ rbf,
                                                  const f32x4* __restrict__ cst,
                                                  const float* __restrict__ sp) {
  __shared__ unsigned char lds[32768];
  int tid = threadIdx.x;
  int bid = blockIdx.x;
  int sbid = ((bid & 7) << 8) | (bid >> 3);   // XCD x -> image x, rows sequential
  int p0 = sbid << 7;
  int b_img = p0 >> 15, loc0 = p0 & 32767;
  {
    int pb = tid & 7, cq = tid >> 3;
    int c4 = cq << 2;
    int kc = cq >> 3, lgr = (cq >> 1) & 3, hlf = cq & 1;
    const unsigned char* ib = in + (((size_t)(b_img << 7)) << 15) + loc0 + (pb << 4);
    u32x4 t0 = *(const u32x4*)(ib + ((size_t)(c4 + 0) << 15));
    u32x4 t1 = *(const u32x4*)(ib + ((size_t)(c4 + 1) << 15));
    u32x4 t2 = *(const u32x4*)(ib + ((size_t)(c4 + 2) << 15));
    u32x4 t3 = *(const u32x4*)(ib + ((size_t)(c4 + 3) << 15));
    int swz = (pb & 7) << 4;
    #pragma unroll
    for (int s = 0; s < 16; s++) {
      int wrd = s >> 2, sh8 = (s & 3) << 3;
      unsigned int chw = ((t0[wrd] >> sh8) & 0xffu)
                       | (((t1[wrd] >> sh8) & 0xffu) << 8)
                       | (((t2[wrd] >> sh8) & 0xffu) << 16)
                       | (((t3[wrd] >> sh8) & 0xffu) << 24);
      unsigned int lo, hi;
      cvt2(chw, lo, hi);
      int ad = ((((((pb << 2) + kc) << 6) | s | (lgr << 4)) << 4) + (hlf << 3)) ^ swz;
      *(u32x2*)(lds + ad) = u32x2{lo, hi};
    }
  }
  __syncthreads();
  int l = tid & 63, wv = tid >> 6;
  int ob = wv << 5;                          // wave owns 32 output channels
  bf16x8 af[2][4];
  #pragma unroll
  for (int ot = 0; ot < 2; ot++)
    #pragma unroll
    for (int kc = 0; kc < 4; kc++) {
      int o = ob + (ot << 4) + (l & 15);
      int k = (kc << 5) + ((l >> 4) << 3);
      af[ot][kc] = *(const bf16x8*)(rbf + o * 128 + k);
    }
  f32x4 acc[2][8];
  #pragma unroll
  for (int ot = 0; ot < 2; ot++)
    #pragma unroll
    for (int pt = 0; pt < 8; pt++) acc[ot][pt] = f32x4{0.f, 0.f, 0.f, 0.f};
  #pragma unroll
  for (int kc = 0; kc < 4; kc++) {
    bf16x8 bb[8];
    #pragma unroll
    for (int pt = 0; pt < 8; pt++)
      bb[pt] = *(const bf16x8*)(lds + (((((((pt << 2) + kc) << 6)) + l) << 4) ^ ((pt & 7) << 4)));
    #pragma unroll
    for (int ot = 0; ot < 2; ot++)
      #pragma unroll
      for (int pt = 0; pt < 8; pt++)
        acc[ot][pt] = __builtin_amdgcn_mfma_f32_16x16x32_bf16(af[ot][kc], bb[pt], acc[ot][pt], 0, 0, 0);
  }
  float s_act = *sp;
  float rs = 1.0f / s_act;
  #pragma unroll
  for (int ot = 0; ot < 2; ot++) {
    int o0 = ob + (ot << 4) + ((l >> 4) << 2);
    f32x4 c0 = cst[o0], c1 = cst[o0 + 1], c2 = cst[o0 + 2], c3 = cst[o0 + 3];
    #pragma unroll
    for (int pt = 0; pt < 8; pt++) {
      int p = p0 + (pt << 4) + (l & 15);
      f32x4 a = acc[ot][pt];
      float q0, q1, q2, q3;
      qstep4(bnval(a.x, c0), bnval(a.y, c1), bnval(a.z, c2), bnval(a.w, c3),
             s_act, rs, q0, q1, q2, q3);
      unsigned int pk = (unsigned int)q0 | ((unsigned int)q1 << 8) |
                        ((unsigned int)q2 << 16) | ((unsigned int)q3 << 24);
      *(unsigned int*)(out + (size_t)p * 128 + o0) = pk;
    }
  }
}

// ---------------- dw-conv2 (separate, high-occupancy): sliding window + qstep4 ----------------
// 8192 blocks x 256 thr; thread = (cq -> 4 ch, pg -> 4 consecutive positions).
// Uniform row check; edge-only column predication. fmaf chain = verified r8/r12 order.
__global__ __launch_bounds__(256) void dw2_kernel(const unsigned char* __restrict__ in,
                                                  unsigned char* __restrict__ out,
                                                  const char* __restrict__ ws,
                                                  const float* __restrict__ sp) {
  __shared__ float tabs[1664];
  const float* src = (const float*)(ws + OFF_R3F);
  for (int i = threadIdx.x; i < 1664; i += 256) tabs[i] = src[i];
  __syncthreads();
  int tid = threadIdx.x;
  int cq = tid & 31, pg = tid >> 5;
  int c4 = cq << 2;
  float wk[9][4];
  #pragma unroll
  for (int t = 0; t < 9; t++) {
    wk[t][0] = tabs[t * 128 + c4];     wk[t][1] = tabs[t * 128 + c4 + 1];
    wk[t][2] = tabs[t * 128 + c4 + 2]; wk[t][3] = tabs[t * 128 + c4 + 3];
  }
  const f32x4* cst3 = (const f32x4*)(tabs + 1152);
  f32x4 cs0 = cst3[c4], cs1 = cst3[c4 + 1], cs2 = cst3[c4 + 2], cs3 = cst3[c4 + 3];
  float s_act = *sp;
  float rs = 1.0f / s_act;
  int bid = blockIdx.x;
  int sbid = ((bid & 7) << 10) | (bid >> 3);     // XCD x -> image x
  int pbase = (sbid << 5) + (pg << 2);           // 4 consecutive positions, same h row
  int wbase = pbase & 255, hh = (pbase >> 8) & 127;

  unsigned int xw[3][6];
  #pragma unroll
  for (int r = 0; r < 3; r++) {
    int gh = hh + r - 1;
    if (gh >= 0 && gh <= 127) {
      const unsigned char* rp = in + (size_t)(pbase + (r - 1) * 256) * 128 + c4;
      xw[r][0] = (wbase > 0)   ? *(const unsigned int*)(rp - 128) : 0u;
      xw[r][1] = *(const unsigned int*)(rp);
      xw[r][2] = *(const unsigned int*)(rp + 128);
      xw[r][3] = *(const unsigned int*)(rp + 256);
      xw[r][4] = *(const unsigned int*)(rp + 384);
      xw[r][5] = (wbase < 252) ? *(const unsigned int*)(rp + 512) : 0u;
    } else {
      xw[r][0] = 0u; xw[r][1] = 0u; xw[r][2] = 0u;
      xw[r][3] = 0u; xw[r][4] = 0u; xw[r][5] = 0u;
    }
  }
  #pragma unroll
  for (int j = 0; j < 4; j++) {
    float a0 = 0.f, a1 = 0.f, a2 = 0.f, a3 = 0.f;
    #pragma unroll
    for (int r = 0; r < 3; r++) {
      #pragma unroll
      for (int dwi = 0; dwi < 3; dwi++) {
        unsigned int v = xw[r][j + dwi];
        int t = r * 3 + dwi;
        a0 = fmaf((float)(v & 0xffu),         wk[t][0], a0);
        a1 = fmaf((float)((v >> 8) & 0xffu),  wk[t][1], a1);
        a2 = fmaf((float)((v >> 16) & 0xffu), wk[t][2], a2);
        a3 = fmaf((float)(v >> 24),           wk[t][3], a3);
      }
    }
    float q0, q1, q2, q3;
    qstep4(bnval(a0, cs0), bnval(a1, cs1), bnval(a2, cs2), bnval(a3, cs3),
           s_act, rs, q0, q1, q2, q3);
    unsigned int pk = (unsigned int)q0 | ((unsigned int)q1 << 8) |
                      ((unsigned int)q2 << 16) | ((unsigned int)q3 << 24);
    *(unsigned int*)(out + (size_t)(pbase + j) * 128 + c4) = pk;
  }
}

// ---------------- fused pw2 + BN4 + qrelu + classifier (r9-proven layout + qstep4) ----------------
__global__ __launch_bounds__(256) void pwcls_kernel(const unsigned char* __restrict__ in,
                                                    float* __restrict__ out,
                                                    const unsigned short* __restrict__ rbf,
                                                    const f32x4* __restrict__ cst,
                                                    const float* __restrict__ sp,
                                                    const unsigned short* __restrict__ r5,
                                                    const float2* __restrict__ cst5) {
  __shared__ unsigned char lds[32768];
  int tid = threadIdx.x;
  int bid = blockIdx.x;
  int sbid = ((bid & 7) << 8) | (bid >> 3);   // XCD x -> image x
  int p0 = sbid << 7;
  #pragma unroll
  for (int it = 0; it < 4; it++) {
    int idx = tid + (it << 8);
    int p = idx >> 3, q = idx & 7;
    int kc = q >> 1, lg = (q & 1) << 1, pt = p >> 4;
    u32x4 g = *(const u32x4*)(in + (size_t)(p0 + p) * 128 + q * 16);
    unsigned int a0, a1, a2, a3, a4, a5, a6, a7;
    cvt2(g.x, a0, a1); cvt2(g.y, a2, a3); cvt2(g.z, a4, a5); cvt2(g.w, a6, a7);
    int l1 = (p & 15) | (lg << 4);
    int ad = (((((pt << 2) + kc) << 6) | l1) << 4);
    *(u32x4*)(lds + ad)       = u32x4{a0, a1, a2, a3};
    *(u32x4*)(lds + ad + 256) = u32x4{a4, a5, a6, a7};
  }
  __syncthreads();
  int l = tid & 63, wv = tid >> 6;
  int ob = wv << 5;
  bf16x8 af[2][4];
  #pragma unroll
  for (int ot = 0; ot < 2; ot++)
    #pragma unroll
    for (int kc = 0; kc < 4; kc++) {
      int o = ob + (ot << 4) + (l & 15);
      int k = (kc << 5) + ((l >> 4) << 3);
      af[ot][kc] = *(const bf16x8*)(rbf + o * 128 + k);
    }
  f32x4 acc[2][8];
  #pragma unroll
  for (int ot = 0; ot < 2; ot++)
    #pragma unroll
    for (int pt = 0; pt < 8; pt++) acc[ot][pt] = f32x4{0.f, 0.f, 0.f, 0.f};
  #pragma unroll
  for (int kc = 0; kc < 4; kc++) {
    bf16x8 bb[8];
    #pragma unroll
    for (int pt = 0; pt < 8; pt++)
      bb[pt] = *(const bf16x8*)(lds + ((((((pt << 2) + kc) << 6)) + l) << 4));
    #pragma unroll
    for (int ot = 0; ot < 2; ot++)
      #pragma unroll
      for (int pt = 0; pt < 8; pt++)
        acc[ot][pt] = __builtin_amdgcn_mfma_f32_16x16x32_bf16(af[ot][kc], bb[pt], acc[ot][pt], 0, 0, 0);
  }
  float s_act = *sp;
  float rs = 1.0f / s_act;
  __syncthreads();   // all waves done reading k3 fragments; lds reusable for k4
  {
    int hsel = (l >> 4) & 1;
    #pragma unroll
    for (int ot = 0; ot < 2; ot++) {
      int o0 = ob + (ot << 4) + ((l >> 4) << 2);
      f32x4 c0 = cst[o0], c1 = cst[o0 + 1], c2 = cst[o0 + 2], c3 = cst[o0 + 3];
      int hi = (ot << 1) + ((l >> 4) >> 1);
      int lfrag = (l & 15) | (hi << 4);
      #pragma unroll
      for (int pt = 0; pt < 8; pt++) {
        f32x4 a = acc[ot][pt];
        float k0f, k1f, k2f, k3f;
        qstep4(bnval(a.x, c0), bnval(a.y, c1), bnval(a.z, c2), bnval(a.w, c3),
               s_act, rs, k0f, k1f, k2f, k3f);
        unsigned int w0 = (__builtin_bit_cast(unsigned int, k0f) >> 16) |
                          (__builtin_bit_cast(unsigned int, k1f) & 0xffff0000u);
        unsigned int w1 = (__builtin_bit_cast(unsigned int, k2f) >> 16) |
                          (__builtin_bit_cast(unsigned int, k3f) & 0xffff0000u);
        int ad = (((((pt << 2) + wv) << 6) | lfrag) << 4) + (hsel << 3);
        *(u32x2*)(lds + ad) = u32x2{w0, w1};
      }
    }
  }
  __syncthreads();
  int pt0 = wv << 1;
  bf16x8 af5[2][4];
  #pragma unroll
  for (int ot = 0; ot < 2; ot++)
    #pragma unroll
    for (int kc = 0; kc < 4; kc++) {
      int o = (ot << 4) + (l & 15);
      int k = (kc << 5) + ((l >> 4) << 3);
      af5[ot][kc] = *(const bf16x8*)(r5 + o * 128 + k);
    }
  f32x4 a5[2][2] = {{{0,0,0,0},{0,0,0,0}},{{0,0,0,0},{0,0,0,0}}};
  #pragma unroll
  for (int kc = 0; kc < 4; kc++) {
    bf16x8 b0 = *(const bf16x8*)(lds + ((((((pt0    ) << 2) + kc) << 6) + l) << 4));
    bf16x8 b1 = *(const bf16x8*)(lds + ((((((pt0 + 1) << 2) + kc) << 6) + l) << 4));
    #pragma unroll
    for (int ot = 0; ot < 2; ot++) {
      a5[ot][0] = __builtin_amdgcn_mfma_f32_16x16x32_bf16(af5[ot][kc], b0, a5[ot][0], 0, 0, 0);
      a5[ot][1] = __builtin_amdgcn_mfma_f32_16x16x32_bf16(af5[ot][kc], b1, a5[ot][1], 0, 0, 0);
    }
  }
  #pragma unroll
  for (int ptl = 0; ptl < 2; ptl++) {
    int p = p0 + ((pt0 + ptl) << 4) + (l & 15);
    int bb = p >> 15, hw = p & 32767;
    float* ob2 = out + (((size_t)bb * 19) << 15) + hw;
    #pragma unroll
    for (int ot = 0; ot < 2; ot++) {
      int obase = (ot << 4) + ((l >> 4) << 2);
      f32x4 a = a5[ot][ptl];
      #pragma unroll
      for (int i = 0; i < 4; i++) {
        int o = obase + i;
        if (o < 19) {
          float2 c5 = cst5[o];
          ob2[(size_t)o << 15] = fmaf(a[i], c5.x, c5.y);
        }
      }
    }
  }
}

// ---------------- launch ----------------
extern "C" void kernel_launch(void* const* d_in, const int* in_sizes, int n_in,
                              void* d_out, int out_size, void* d_ws, size_t ws_size,
                              hipStream_t stream) {
  (void)in_sizes; (void)n_in; (void)out_size; (void)ws_size;
  char* ws = (char*)d_ws;
  PArgs P;
  P.dw1  = (const float*)d_in[1];
  P.pw1  = (const float*)d_in[2];
  P.dw2  = (const float*)d_in[3];
  P.pw2  = (const float*)d_in[4];
  P.clsw = (const float*)d_in[5];
  P.clsb = (const float*)d_in[6];
  P.g1 = (const float*)d_in[7];  P.b1 = (const float*)d_in[8];
  P.m1 = (const float*)d_in[9];  P.v1 = (const float*)d_in[10];
  P.g2 = (const float*)d_in[11]; P.b2 = (const float*)d_in[12];
  P.m2 = (const float*)d_in[13]; P.v2 = (const float*)d_in[14];
  P.g3 = (const float*)d_in[15]; P.b3 = (const float*)d_in[16];
  P.m3 = (const float*)d_in[17]; P.v3 = (const float*)d_in[18];
  P.g4 = (const float*)d_in[19]; P.b4 = (const float*)d_in[20];
  P.m4 = (const float*)d_in[21]; P.v4 = (const float*)d_in[22];
  P.s1 = (const float*)d_in[23]; P.s2 = (const float*)d_in[24];
  P.s3 = (const float*)d_in[25]; P.s4 = (const float*)d_in[26];

  const float* x = (const float*)d_in[0];
  unsigned char* bufA = (unsigned char*)(ws + OFF_BUFA);
  unsigned char* bufB = (unsigned char*)(ws + OFF_BUFB);

  prep_kernel<<<544, 64, 0, stream>>>(P, ws);
  dwA_kernel<<<1024, 512, 0, stream>>>(x, ws, P.s1);                       // x -> k1 NCHW u8 (B)
  pwn_kernel<<<2048, 256, 0, stream>>>(bufB, bufA,
      (const unsigned short*)(ws + OFF_R2BF), (const f32x4*)(ws + OFF_CST2), P.s2);  // k1 NCHW -> k2 NHWC (A)
  dw2_kernel<<<8192, 256, 0, stream>>>(bufA, bufB, ws, P.s3);              // k2 -> k3 (B)
  pwcls_kernel<<<2048, 256, 0, stream>>>(bufB, (float*)d_out,
      (const unsigned short*)(ws + OFF_R4BF), (const f32x4*)(ws + OFF_CST4), P.s4,
      (const unsigned short*)(ws + OFF_R5BF), (const float2*)(ws + OFF_CST5));       // k3 -> out
}

// Round 17
// 129.364 us; speedup vs baseline: 1.0536x; 1.0536x over previous
//
#include <hip/hip_runtime.h>

typedef __attribute__((ext_vector_type(4))) float f32x4;
typedef __attribute__((ext_vector_type(8))) short bf16x8;
typedef __attribute__((ext_vector_type(2))) unsigned int u32x2;
typedef __attribute__((ext_vector_type(4))) unsigned int u32x4;

#define EPSV 1e-5f

// workspace layout (bytes)
#define OFF_BUFA 0u
#define OFF_BUFB 33554432u
#define OFF_T    67108864u
#define OFF_WQ1  (OFF_T + 0u)       // f32 [128][12]  (9 taps used)
#define OFF_R3F  (OFF_T + 6144u)    // f32 [9][128]   integer-valued
#define OFF_CST3 (OFF_T + 10752u)   // f32x4 [128]
#define OFF_CST1 (OFF_T + 12800u)   // f32x4 [128]
#define OFF_R2BF (OFF_T + 14848u)   // bf16 [128][128]
#define OFF_CST2 (OFF_T + 47616u)   // f32x4 [128]
#define OFF_R4BF (OFF_T + 49664u)   // bf16 [128][128]
#define OFF_CST4 (OFF_T + 82432u)   // f32x4 [128]
#define OFF_R5BF (OFF_T + 84480u)   // bf16 [32][128] (rows 19..31 zero)
#define OFF_CST5 (OFF_T + 92672u)   // float2 [32]

struct PArgs {
  const float *dw1, *pw1, *dw2, *pw2, *clsw, *clsb;
  const float *g1, *b1, *m1, *v1;
  const float *g2, *b2, *m2, *v2;
  const float *g3, *b3, *m3, *v3;
  const float *g4, *b4, *m4, *v4;
  const float *s1, *s2, *s3, *s4;
};

__device__ __forceinline__ unsigned short f2bf(float f) {
  return (unsigned short)(__builtin_bit_cast(unsigned int, f) >> 16);
}
__device__ __forceinline__ float clip7(float r) { return fminf(fmaxf(r, -7.f), 7.f); }

// BN-transformed value; expression identical to all previous rounds.
__device__ __forceinline__ float bnval(float a, f32x4 c) {
  return (a * c.x - c.z) * c.y + c.w;
}

// Quantize 4 values: fast path u = t*(1/s) + rint; if any lane lands within
// 3e-5 of a half-integer (fast-path abs error <= ~4e-6 for |u|<=16), the wave
// recomputes with exact division -> emitted k bit-identical to exact path.
__device__ __forceinline__ void qstep4(float t0, float t1, float t2, float t3,
                                       float s, float rs,
                                       float &k0, float &k1, float &k2, float &k3) {
  float u0 = t0 * rs, u1 = t1 * rs, u2 = t2 * rs, u3 = t3 * rs;
  float f0 = rintf(u0), f1 = rintf(u1), f2 = rintf(u2), f3 = rintf(u3);
  float d0 = fabsf(fabsf(u0 - f0) - 0.5f);
  float d1 = fabsf(fabsf(u1 - f1) - 0.5f);
  float d2 = fabsf(fabsf(u2 - f2) - 0.5f);
  float d3 = fabsf(fabsf(u3 - f3) - 0.5f);
  bool near = (d0 < 3e-5f) | (d1 < 3e-5f) | (d2 < 3e-5f) | (d3 < 3e-5f);
  if (__any(near)) {
    f0 = rintf(t0 / s); f1 = rintf(t1 / s);
    f2 = rintf(t2 / s); f3 = rintf(t3 / s);
  }
  k0 = fminf(fmaxf(f0, 0.f), 15.f);
  k1 = fminf(fmaxf(f1, 0.f), 15.f);
  k2 = fminf(fmaxf(f2, 0.f), 15.f);
  k3 = fminf(fmaxf(f3, 0.f), 15.f);
}

// 4 u8 -> 2 dwords of packed bf16
__device__ __forceinline__ void cvt2(unsigned int d, unsigned int &lo, unsigned int &hi) {
  float f0 = (float)(d & 0xffu);
  float f1 = (float)((d >> 8) & 0xffu);
  float f2 = (float)((d >> 16) & 0xffu);
  float f3 = (float)(d >> 24);
  lo = (__builtin_bit_cast(unsigned int, f0) >> 16) | (__builtin_bit_cast(unsigned int, f1) & 0xffff0000u);
  hi = (__builtin_bit_cast(unsigned int, f2) >> 16) | (__builtin_bit_cast(unsigned int, f3) & 0xffff0000u);
}

__device__ __forceinline__ float wmax16(float v) {
  #pragma unroll
  for (int s = 1; s < 16; s <<= 1) v = fmaxf(v, __shfl_xor(v, s));
  return v;
}
__device__ __forceinline__ float wmax64(float v) {
  #pragma unroll
  for (int s = 1; s < 64; s <<= 1) v = fmaxf(v, __shfl_xor(v, s));
  return v;
}

// ---------------- prep: quantize weights, fold BN constants ----------------
__global__ __launch_bounds__(64) void prep_kernel(PArgs P, char* __restrict__ ws) {
  int bi = blockIdx.x, l = threadIdx.x;
  float* wq1 = (float*)(ws + OFF_WQ1);
  float* r3f = (float*)(ws + OFF_R3F);
  f32x4* cst1 = (f32x4*)(ws + OFF_CST1);
  f32x4* cst2 = (f32x4*)(ws + OFF_CST2);
  f32x4* cst3 = (f32x4*)(ws + OFF_CST3);
  f32x4* cst4 = (f32x4*)(ws + OFF_CST4);
  unsigned short* r2 = (unsigned short*)(ws + OFF_R2BF);
  unsigned short* r4 = (unsigned short*)(ws + OFF_R4BF);
  unsigned short* r5 = (unsigned short*)(ws + OFF_R5BF);
  float2* cst5 = (float2*)(ws + OFF_CST5);

  if (bi < 128) {
    int c = bi;
    float w = (l < 9) ? P.dw1[c * 9 + l] : 0.f;
    float mx = wmax16(fabsf(w));
    float sq = fmaxf(mx / 7.0f, 1e-8f);
    if (l < 9) wq1[c * 12 + l] = clip7(rintf(w / sq)) * sq;
    if (l == 0) {
      float sc = P.g1[c] / sqrtf(P.v1[c] + EPSV);
      cst1[c] = f32x4{1.f, sc, P.m1[c], P.b1[c]};
    }
  } else if (bi < 256) {
    int o = bi - 128;
    float w0 = P.pw1[o * 128 + l], w1 = P.pw1[o * 128 + 64 + l];
    float mx = wmax64(fmaxf(fabsf(w0), fabsf(w1)));
    float sq = fmaxf(mx / 7.0f, 1e-8f);
    r2[o * 128 + l]      = f2bf(clip7(rintf(w0 / sq)));
    r2[o * 128 + 64 + l] = f2bf(clip7(rintf(w1 / sq)));
    if (l == 0) {
      float sc = P.g2[o] / sqrtf(P.v2[o] + EPSV);
      cst2[o] = f32x4{P.s1[0] * sq, sc, P.m2[o], P.b2[o]};
    }
  } else if (bi < 384) {
    int c = bi - 256;
    float w = (l < 9) ? P.dw2[c * 9 + l] : 0.f;
    float mx = wmax16(fabsf(w));
    float sq = fmaxf(mx / 7.0f, 1e-8f);
    if (l < 9) r3f[l * 128 + c] = clip7(rintf(w / sq));
    if (l == 0) {
      float sc = P.g3[c] / sqrtf(P.v3[c] + EPSV);
      cst3[c] = f32x4{P.s2[0] * sq, sc, P.m3[c], P.b3[c]};
    }
  } else if (bi < 512) {
    int o = bi - 384;
    float w0 = P.pw2[o * 128 + l], w1 = P.pw2[o * 128 + 64 + l];
    float mx = wmax64(fmaxf(fabsf(w0), fabsf(w1)));
    float sq = fmaxf(mx / 7.0f, 1e-8f);
    r4[o * 128 + l]      = f2bf(clip7(rintf(w0 / sq)));
    r4[o * 128 + 64 + l] = f2bf(clip7(rintf(w1 / sq)));
    if (l == 0) {
      float sc = P.g4[o] / sqrtf(P.v4[o] + EPSV);
      cst4[o] = f32x4{P.s3[0] * sq, sc, P.m4[o], P.b4[o]};
    }
  } else {
    int o = bi - 512;
    if (o < 19) {
      float w0 = P.clsw[o * 128 + l], w1 = P.clsw[o * 128 + 64 + l];
      float mx = wmax64(fmaxf(fabsf(w0), fabsf(w1)));
      float sq = fmaxf(mx / 7.0f, 1e-8f);
      r5[o * 128 + l]      = f2bf(clip7(rintf(w0 / sq)));
      r5[o * 128 + 64 + l] = f2bf(clip7(rintf(w1 / sq)));
      if (l == 0) {
        float A5 = P.s4[0] * sq;
        float bq = rintf(P.clsb[o] / A5) * A5;
        cst5[o] = make_float2(A5, bq);
      }
    } else {
      r5[o * 128 + l] = 0; r5[o * 128 + 64 + l] = 0;
      if (l == 0) cst5[o] = make_float2(0.f, 0.f);
    }
  }
}

// ---------------- dw-conv1 phase A: per-plane streaming, rolling 3-row window ----------------
__global__ __launch_bounds__(512) void dwA_kernel(const float* __restrict__ x,
                                                  char* __restrict__ ws,
                                                  const float* __restrict__ s1p) {
  int bid = blockIdx.x;
  int b = bid & 7, c = bid >> 3;              // XCD x owns image b=x
  int tid = threadIdx.x;
  int wq = tid & 63, wv = tid >> 6;
  int w0 = wq << 2;
  int h0 = wv << 4;
  const float* wp = (const float*)(ws + OFF_WQ1) + c * 12;
  float k0 = wp[0], k1 = wp[1], k2 = wp[2], k3 = wp[3], k4 = wp[4],
        k5 = wp[5], k6 = wp[6], k7 = wp[7], k8 = wp[8];
  f32x4 cs = ((const f32x4*)(ws + OFF_CST1))[c];
  float s_act = *s1p;
  float rs = 1.0f / s_act;
  const float* plane = x + (((size_t)((b << 7) | c)) << 15);
  unsigned char* oplane = (unsigned char*)(ws + OFF_BUFB) + (((size_t)((b << 7) | c)) << 15);

  f32x4 vm = {0.f, 0.f, 0.f, 0.f};
  if (h0 > 0) vm = *(const f32x4*)(plane + ((h0 - 1) << 8) + w0);
  f32x4 v0 = *(const f32x4*)(plane + (h0 << 8) + w0);
  f32x4 vp = *(const f32x4*)(plane + ((h0 + 1) << 8) + w0);
  float lm = __shfl_up(vm.w, 1), l0 = __shfl_up(v0.w, 1), lp = __shfl_up(vp.w, 1);
  float rm = __shfl_down(vm.x, 1), r0 = __shfl_down(v0.x, 1), rp = __shfl_down(vp.x, 1);
  if (wq == 0)  { lm = 0.f; l0 = 0.f; lp = 0.f; }
  if (wq == 63) { rm = 0.f; r0 = 0.f; rp = 0.f; }

  #pragma unroll 4
  for (int i = 0; i < 16; i++) {
    int h = h0 + i;
    float y0 = 0.f, y1 = 0.f, y2 = 0.f, y3 = 0.f;
    // row -1 (k0,k1,k2) then row 0 (k3,k4,k5) then row +1 (k6,k7,k8) — r1 order
    y0 = fmaf(lm,   k0, y0); y0 = fmaf(vm.x, k1, y0); y0 = fmaf(vm.y, k2, y0);
    y1 = fmaf(vm.x, k0, y1); y1 = fmaf(vm.y, k1, y1); y1 = fmaf(vm.z, k2, y1);
    y2 = fmaf(vm.y, k0, y2); y2 = fmaf(vm.z, k1, y2); y2 = fmaf(vm.w, k2, y2);
    y3 = fmaf(vm.z, k0, y3); y3 = fmaf(vm.w, k1, y3); y3 = fmaf(rm,   k2, y3);

    y0 = fmaf(l0,   k3, y0); y0 = fmaf(v0.x, k4, y0); y0 = fmaf(v0.y, k5, y0);
    y1 = fmaf(v0.x, k3, y1); y1 = fmaf(v0.y, k4, y1); y1 = fmaf(v0.z, k5, y1);
    y2 = fmaf(v0.y, k3, y2); y2 = fmaf(v0.z, k4, y2); y2 = fmaf(v0.w, k5, y2);
    y3 = fmaf(v0.z, k3, y3); y3 = fmaf(v0.w, k4, y3); y3 = fmaf(r0,   k5, y3);

    y0 = fmaf(lp,   k6, y0); y0 = fmaf(vp.x, k7, y0); y0 = fmaf(vp.y, k8, y0);
    y1 = fmaf(vp.x, k6, y1); y1 = fmaf(vp.y, k7, y1); y1 = fmaf(vp.z, k8, y1);
    y2 = fmaf(vp.y, k6, y2); y2 = fmaf(vp.z, k7, y2); y2 = fmaf(vp.w, k8, y2);
    y3 = fmaf(vp.z, k6, y3); y3 = fmaf(vp.w, k7, y3); y3 = fmaf(rp,   k8, y3);

    float q0, q1, q2, q3;
    qstep4(bnval(y0, cs), bnval(y1, cs), bnval(y2, cs), bnval(y3, cs),
           s_act, rs, q0, q1, q2, q3);
    unsigned int pk = (unsigned int)q0 | ((unsigned int)q1 << 8) |
                      ((unsigned int)q2 << 16) | ((unsigned int)q3 << 24);
    *(unsigned int*)(oplane + (h << 8) + w0) = pk;

    // shift window; load row h+2 for next iteration
    vm = v0; lm = l0; rm = r0;
    v0 = vp; l0 = lp; r0 = rp;
    f32x4 nv = {0.f, 0.f, 0.f, 0.f};
    if (i < 15 && h + 2 < 128) nv = *(const f32x4*)(plane + ((h + 2) << 8) + w0);
    vp = nv;
    float nl = __shfl_up(nv.w, 1), nr = __shfl_down(nv.x, 1);
    if (wq == 0)  nl = 0.f;
    if (wq == 63) nr = 0.f;
    lp = nl; rp = nr;
  }
}

// ---------------- pw1 from NCHW: staging does the transpose in-register ----------------
__global__ __launch_bounds__(256) void pwn_kernel(const unsigned char* __restrict__ in,
                                                  unsigned char* __restrict__ out,
                                                  const unsigned short* __restrict__ rbf,
                                                  const f32x4* __restrict__ cst,
                                                  const float* __restrict__ sp) {
  __shared__ unsigned char lds[32768];
  int tid = threadIdx.x;
  int bid = blockIdx.x;
  int sbid = ((bid & 7) << 8) | (bid >> 3);   // XCD x -> image x, rows sequential
  int p0 = sbid << 7;
  int b_img = p0 >> 15, loc0 = p0 & 32767;
  {
    int pb = tid & 7, cq = tid >> 3;
    int c4 = cq << 2;
    int kc = cq >> 3, lgr = (cq >> 1) & 3, hlf = cq & 1;
    const unsigned char* ib = in + (((size_t)(b_img << 7)) << 15) + loc0 + (pb << 4);
    u32x4 t0 = *(const u32x4*)(ib + ((size_t)(c4 + 0) << 15));
    u32x4 t1 = *(const u32x4*)(ib + ((size_t)(c4 + 1) << 15));
    u32x4 t2 = *(const u32x4*)(ib + ((size_t)(c4 + 2) << 15));
    u32x4 t3 = *(const u32x4*)(ib + ((size_t)(c4 + 3) << 15));
    int swz = (pb & 7) << 4;
    #pragma unroll
    for (int s = 0; s < 16; s++) {
      int wrd = s >> 2, sh8 = (s & 3) << 3;
      unsigned int chw = ((t0[wrd] >> sh8) & 0xffu)
                       | (((t1[wrd] >> sh8) & 0xffu) << 8)
                       | (((t2[wrd] >> sh8) & 0xffu) << 16)
                       | (((t3[wrd] >> sh8) & 0xffu) << 24);
      unsigned int lo, hi;
      cvt2(chw, lo, hi);
      int ad = ((((((pb << 2) + kc) << 6) | s | (lgr << 4)) << 4) + (hlf << 3)) ^ swz;
      *(u32x2*)(lds + ad) = u32x2{lo, hi};
    }
  }
  __syncthreads();
  int l = tid & 63, wv = tid >> 6;
  int ob = wv << 5;                          // wave owns 32 output channels
  bf16x8 af[2][4];
  #pragma unroll
  for (int ot = 0; ot < 2; ot++)
    #pragma unroll
    for (int kc = 0; kc < 4; kc++) {
      int o = ob + (ot << 4) + (l & 15);
      int k = (kc << 5) + ((l >> 4) << 3);
      af[ot][kc] = *(const bf16x8*)(rbf + o * 128 + k);
    }
  f32x4 acc[2][8];
  #pragma unroll
  for (int ot = 0; ot < 2; ot++)
    #pragma unroll
    for (int pt = 0; pt < 8; pt++) acc[ot][pt] = f32x4{0.f, 0.f, 0.f, 0.f};
  #pragma unroll
  for (int kc = 0; kc < 4; kc++) {
    bf16x8 bb[8];
    #pragma unroll
    for (int pt = 0; pt < 8; pt++)
      bb[pt] = *(const bf16x8*)(lds + (((((((pt << 2) + kc) << 6)) + l) << 4) ^ ((pt & 7) << 4)));
    #pragma unroll
    for (int ot = 0; ot < 2; ot++)
      #pragma unroll
      for (int pt = 0; pt < 8; pt++)
        acc[ot][pt] = __builtin_amdgcn_mfma_f32_16x16x32_bf16(af[ot][kc], bb[pt], acc[ot][pt], 0, 0, 0);
  }
  float s_act = *sp;
  float rs = 1.0f / s_act;
  #pragma unroll
  for (int ot = 0; ot < 2; ot++) {
    int o0 = ob + (ot << 4) + ((l >> 4) << 2);
    f32x4 c0 = cst[o0], c1 = cst[o0 + 1], c2 = cst[o0 + 2], c3 = cst[o0 + 3];
    #pragma unroll
    for (int pt = 0; pt < 8; pt++) {
      int p = p0 + (pt << 4) + (l & 15);
      f32x4 a = acc[ot][pt];
      float q0, q1, q2, q3;
      qstep4(bnval(a.x, c0), bnval(a.y, c1), bnval(a.z, c2), bnval(a.w, c3),
             s_act, rs, q0, q1, q2, q3);
      unsigned int pk = (unsigned int)q0 | ((unsigned int)q1 << 8) |
                        ((unsigned int)q2 << 16) | ((unsigned int)q3 << 24);
      *(unsigned int*)(out + (size_t)p * 128 + o0) = pk;
    }
  }
}

// ---------------- fused dw2 + BN3 + qrelu + pw2 + BN4 + qrelu + classifier ----------------
// 64-position blocks (4096 total): 32KB LDS (k3 [0,16K), k4 [+16K)) -> ~2x blocks/CU,
// cross-block phase overlap. All per-position numeric chains identical to r13.
__global__ __launch_bounds__(256) void dw2pwcls_kernel(const unsigned char* __restrict__ in,
                                                       float* __restrict__ out,
                                                       const char* __restrict__ ws,
                                                       const unsigned short* __restrict__ rbf,
                                                       const f32x4* __restrict__ cst,
                                                       const float* __restrict__ s3p,
                                                       const float* __restrict__ s4p,
                                                       const unsigned short* __restrict__ r5,
                                                       const float2* __restrict__ cst5) {
  __shared__ unsigned char lds[32768];
  int tid = threadIdx.x;
  int bid = blockIdx.x;
  int sbid = ((bid & 7) << 9) | (bid >> 3);   // XCD x -> image x, chunks sequential
  int p0 = sbid << 6;                         // 64 consecutive positions, single h row
  // ---- phase 1: dw2 sliding window -> bf16 fragments (swizzled), 2 passes ----
  {
    int cq = tid & 31, pg = tid >> 5;
    int c4 = cq << 2;
    const float* r3f = (const float*)(ws + OFF_R3F);
    float wk[9][4];
    #pragma unroll
    for (int t = 0; t < 9; t++) {
      wk[t][0] = r3f[t * 128 + c4];     wk[t][1] = r3f[t * 128 + c4 + 1];
      wk[t][2] = r3f[t * 128 + c4 + 2]; wk[t][3] = r3f[t * 128 + c4 + 3];
    }
    const f32x4* cst3 = (const f32x4*)(ws + OFF_CST3);
    f32x4 cs0 = cst3[c4], cs1 = cst3[c4 + 1], cs2 = cst3[c4 + 2], cs3 = cst3[c4 + 3];
    float s_act3 = *s3p;
    float rs3 = 1.0f / s_act3;
    int kc = c4 >> 5, hi = (c4 >> 3) & 3, hlf = (c4 >> 2) & 1;
    int g = hi | ((kc & 1) << 2);
    int hh = (p0 >> 8) & 127;          // block-uniform row index
    #pragma unroll
    for (int ps = 0; ps < 2; ps++) {
      int pbase = p0 + (ps << 5) + (pg << 2);   // 4 consecutive positions
      int wbase = pbase & 255;
      unsigned int xw[3][6];
      #pragma unroll
      for (int r = 0; r < 3; r++) {
        int gh = hh + r - 1;
        if (gh >= 0 && gh <= 127) {    // uniform branch
          const unsigned char* rp = in + (size_t)(pbase + (r - 1) * 256) * 128 + c4;
          xw[r][0] = (wbase > 0)   ? *(const unsigned int*)(rp - 128) : 0u;
          xw[r][1] = *(const unsigned int*)(rp);
          xw[r][2] = *(const unsigned int*)(rp + 128);
          xw[r][3] = *(const unsigned int*)(rp + 256);
          xw[r][4] = *(const unsigned int*)(rp + 384);
          xw[r][5] = (wbase < 252) ? *(const unsigned int*)(rp + 512) : 0u;
        } else {
          xw[r][0] = 0u; xw[r][1] = 0u; xw[r][2] = 0u;
          xw[r][3] = 0u; xw[r][4] = 0u; xw[r][5] = 0u;
        }
      }
      #pragma unroll
      for (int j = 0; j < 4; j++) {
        float a0 = 0.f, a1 = 0.f, a2 = 0.f, a3 = 0.f;
        #pragma unroll
        for (int r = 0; r < 3; r++) {
          #pragma unroll
          for (int dwi = 0; dwi < 3; dwi++) {
            unsigned int v = xw[r][j + dwi];
            int t = r * 3 + dwi;
            a0 = fmaf((float)(v & 0xffu),         wk[t][0], a0);
            a1 = fmaf((float)((v >> 8) & 0xffu),  wk[t][1], a1);
            a2 = fmaf((float)((v >> 16) & 0xffu), wk[t][2], a2);
            a3 = fmaf((float)(v >> 24),           wk[t][3], a3);
          }
        }
        float k0f, k1f, k2f, k3f;
        qstep4(bnval(a0, cs0), bnval(a1, cs1), bnval(a2, cs2), bnval(a3, cs3),
               s_act3, rs3, k0f, k1f, k2f, k3f);
        // bf16(small int float) == cvt2-of-u8 path exactly
        unsigned int wlo = (__builtin_bit_cast(unsigned int, k0f) >> 16) |
                           (__builtin_bit_cast(unsigned int, k1f) & 0xffff0000u);
        unsigned int whi = (__builtin_bit_cast(unsigned int, k2f) >> 16) |
                           (__builtin_bit_cast(unsigned int, k3f) & 0xffff0000u);
        int p_local = (ps << 5) + (pg << 2) + j;
        int pt = p_local >> 4, pl = p_local & 15;
        int slot = (pl ^ g) | (hi << 4);
        int ad = (((((pt << 2) + kc) << 6) | slot) << 4) + (hlf << 3);
        *(u32x2*)(lds + ad) = u32x2{wlo, whi};
      }
    }
  }
  __syncthreads();
  // ---- phase 2: pw2 MFMA (reads swizzled fragments), pt in [0,4) ----
  int l = tid & 63, wv = tid >> 6;
  int ob = wv << 5;
  bf16x8 af[2][4];
  #pragma unroll
  for (int ot = 0; ot < 2; ot++)
    #pragma unroll
    for (int kc = 0; kc < 4; kc++) {
      int o = ob + (ot << 4) + (l & 15);
      int k = (kc << 5) + ((l >> 4) << 3);
      af[ot][kc] = *(const bf16x8*)(rbf + o * 128 + k);
    }
  f32x4 acc[2][4];
  #pragma unroll
  for (int ot = 0; ot < 2; ot++)
    #pragma unroll
    for (int pt = 0; pt < 4; pt++) acc[ot][pt] = f32x4{0.f, 0.f, 0.f, 0.f};
  #pragma unroll
  for (int kc = 0; kc < 4; kc++) {
    int gg = (l >> 4) | ((kc & 1) << 2);
    bf16x8 bb[4];
    #pragma unroll
    for (int pt = 0; pt < 4; pt++)
      bb[pt] = *(const bf16x8*)(lds + ((((((pt << 2) + kc) << 6)) | (l ^ gg)) << 4));
    #pragma unroll
    for (int ot = 0; ot < 2; ot++)
      #pragma unroll
      for (int pt = 0; pt < 4; pt++)
        acc[ot][pt] = __builtin_amdgcn_mfma_f32_16x16x32_bf16(af[ot][kc], bb[pt], acc[ot][pt], 0, 0, 0);
  }
  float s_act4 = *s4p;
  float rs4 = 1.0f / s_act4;
  // ---- phase 3: BN4+qrelu -> k4 bf16 fragments at +16K (disjoint region, no barrier) ----
  {
    int hsel = (l >> 4) & 1;
    #pragma unroll
    for (int ot = 0; ot < 2; ot++) {
      int o0 = ob + (ot << 4) + ((l >> 4) << 2);
      f32x4 c0 = cst[o0], c1 = cst[o0 + 1], c2 = cst[o0 + 2], c3 = cst[o0 + 3];
      int hi = (ot << 1) + ((l >> 4) >> 1);
      int lfrag = (l & 15) | (hi << 4);
      #pragma unroll
      for (int pt = 0; pt < 4; pt++) {
        f32x4 a = acc[ot][pt];
        float k0f, k1f, k2f, k3f;
        qstep4(bnval(a.x, c0), bnval(a.y, c1), bnval(a.z, c2), bnval(a.w, c3),
               s_act4, rs4, k0f, k1f, k2f, k3f);
        unsigned int w0 = (__builtin_bit_cast(unsigned int, k0f) >> 16) |
                          (__builtin_bit_cast(unsigned int, k1f) & 0xffff0000u);
        unsigned int w1 = (__builtin_bit_cast(unsigned int, k2f) >> 16) |
                          (__builtin_bit_cast(unsigned int, k3f) & 0xffff0000u);
        int ad = 16384 + ((((((pt << 2) + wv) << 6) | lfrag) << 4) + (hsel << 3));
        *(u32x2*)(lds + ad) = u32x2{w0, w1};
      }
    }
  }
  __syncthreads();
  // ---- phase 4: classifier MFMA (k4 fragments at +16K); wave wv owns tile pt0=wv ----
  int pt0 = wv;
  bf16x8 af5[2][4];
  #pragma unroll
  for (int ot = 0; ot < 2; ot++)
    #pragma unroll
    for (int kc = 0; kc < 4; kc++) {
      int o = (ot << 4) + (l & 15);
      int k = (kc << 5) + ((l >> 4) << 3);
      af5[ot][kc] = *(const bf16x8*)(r5 + o * 128 + k);
    }
  f32x4 a5[2] = {{0,0,0,0},{0,0,0,0}};
  #pragma unroll
  for (int kc = 0; kc < 4; kc++) {
    bf16x8 b0 = *(const bf16x8*)(lds + 16384 + ((((((pt0) << 2) + kc) << 6) + l) << 4));
    a5[0] = __builtin_amdgcn_mfma_f32_16x16x32_bf16(af5[0][kc], b0, a5[0], 0, 0, 0);
    a5[1] = __builtin_amdgcn_mfma_f32_16x16x32_bf16(af5[1][kc], b0, a5[1], 0, 0, 0);
  }
  {
    int p = p0 + (pt0 << 4) + (l & 15);
    int bb = p >> 15, hw = p & 32767;
    float* ob2 = out + (((size_t)bb * 19) << 15) + hw;
    #pragma unroll
    for (int ot = 0; ot < 2; ot++) {
      int obase = (ot << 4) + ((l >> 4) << 2);
      f32x4 a = a5[ot];
      #pragma unroll
      for (int i = 0; i < 4; i++) {
        int o = obase + i;
        if (o < 19) {
          float2 c5 = cst5[o];
          ob2[(size_t)o << 15] = fmaf(a[i], c5.x, c5.y);
        }
      }
    }
  }
}

// ---------------- launch ----------------
extern "C" void kernel_launch(void* const* d_in, const int* in_sizes, int n_in,
                              void* d_out, int out_size, void* d_ws, size_t ws_size,
                              hipStream_t stream) {
  (void)in_sizes; (void)n_in; (void)out_size; (void)ws_size;
  char* ws = (char*)d_ws;
  PArgs P;
  P.dw1  = (const float*)d_in[1];
  P.pw1  = (const float*)d_in[2];
  P.dw2  = (const float*)d_in[3];
  P.pw2  = (const float*)d_in[4];
  P.clsw = (const float*)d_in[5];
  P.clsb = (const float*)d_in[6];
  P.g1 = (const float*)d_in[7];  P.b1 = (const float*)d_in[8];
  P.m1 = (const float*)d_in[9];  P.v1 = (const float*)d_in[10];
  P.g2 = (const float*)d_in[11]; P.b2 = (const float*)d_in[12];
  P.m2 = (const float*)d_in[13]; P.v2 = (const float*)d_in[14];
  P.g3 = (const float*)d_in[15]; P.b3 = (const float*)d_in[16];
  P.m3 = (const float*)d_in[17]; P.v3 = (const float*)d_in[18];
  P.g4 = (const float*)d_in[19]; P.b4 = (const float*)d_in[20];
  P.m4 = (const float*)d_in[21]; P.v4 = (const float*)d_in[22];
  P.s1 = (const float*)d_in[23]; P.s2 = (const float*)d_in[24];
  P.s3 = (const float*)d_in[25]; P.s4 = (const float*)d_in[26];

  const float* x = (const float*)d_in[0];
  unsigned char* bufA = (unsigned char*)(ws + OFF_BUFA);
  unsigned char* bufB = (unsigned char*)(ws + OFF_BUFB);

  prep_kernel<<<544, 64, 0, stream>>>(P, ws);
  dwA_kernel<<<1024, 512, 0, stream>>>(x, ws, P.s1);                       // x -> k1 NCHW u8 (B)
  pwn_kernel<<<2048, 256, 0, stream>>>(bufB, bufA,
      (const unsigned short*)(ws + OFF_R2BF), (const f32x4*)(ws + OFF_CST2), P.s2);  // k1 NCHW -> k2 NHWC (A)
  dw2pwcls_kernel<<<4096, 256, 0, stream>>>(bufA, (float*)d_out, ws,
      (const unsigned short*)(ws + OFF_R4BF), (const f32x4*)(ws + OFF_CST4),
      P.s3, P.s4,
      (const unsigned short*)(ws + OFF_R5BF), (const float2*)(ws + OFF_CST5));       // k2 -> out
}

// Round 18
// 127.459 us; speedup vs baseline: 1.0693x; 1.0149x over previous
//
#include <hip/hip_runtime.h>

typedef __attribute__((ext_vector_type(4))) float f32x4;
typedef __attribute__((ext_vector_type(8))) short bf16x8;
typedef __attribute__((ext_vector_type(2))) unsigned int u32x2;
typedef __attribute__((ext_vector_type(4))) unsigned int u32x4;

#define EPSV 1e-5f

// workspace layout (bytes)
#define OFF_BUFA 0u
#define OFF_BUFB 33554432u
#define OFF_T    67108864u
#define OFF_WQ1  (OFF_T + 0u)       // f32 [128][12]  (9 taps used)
#define OFF_R3F  (OFF_T + 6144u)    // f32 [9][128]   integer-valued
#define OFF_CST3 (OFF_T + 10752u)   // f32x4 [128]
#define OFF_CST1 (OFF_T + 12800u)   // f32x4 [128]
#define OFF_R2BF (OFF_T + 14848u)   // bf16 [128][128]
#define OFF_CST2 (OFF_T + 47616u)   // f32x4 [128]
#define OFF_R4BF (OFF_T + 49664u)   // bf16 [128][128]
#define OFF_CST4 (OFF_T + 82432u)   // f32x4 [128]
#define OFF_R5BF (OFF_T + 84480u)   // bf16 [32][128] (rows 19..31 zero)
#define OFF_CST5 (OFF_T + 92672u)   // float2 [32]

struct PArgs {
  const float *dw1, *pw1, *dw2, *pw2, *clsw, *clsb;
  const float *g1, *b1, *m1, *v1;
  const float *g2, *b2, *m2, *v2;
  const float *g3, *b3, *m3, *v3;
  const float *g4, *b4, *m4, *v4;
  const float *s1, *s2, *s3, *s4;
};

__device__ __forceinline__ unsigned short f2bf(float f) {
  return (unsigned short)(__builtin_bit_cast(unsigned int, f) >> 16);
}
__device__ __forceinline__ float clip7(float r) { return fminf(fmaxf(r, -7.f), 7.f); }

// BN-transformed value; expression identical to all previous rounds.
__device__ __forceinline__ float bnval(float a, f32x4 c) {
  return (a * c.x - c.z) * c.y + c.w;
}

// Quantize 4 values: fast path u = t*(1/s) + rint; if any lane lands within
// 3e-5 of a half-integer (fast-path abs error <= ~4e-6 for |u|<=16), the wave
// recomputes with exact division -> emitted k bit-identical to exact path.
__device__ __forceinline__ void qstep4(float t0, float t1, float t2, float t3,
                                       float s, float rs,
                                       float &k0, float &k1, float &k2, float &k3) {
  float u0 = t0 * rs, u1 = t1 * rs, u2 = t2 * rs, u3 = t3 * rs;
  float f0 = rintf(u0), f1 = rintf(u1), f2 = rintf(u2), f3 = rintf(u3);
  float d0 = fabsf(fabsf(u0 - f0) - 0.5f);
  float d1 = fabsf(fabsf(u1 - f1) - 0.5f);
  float d2 = fabsf(fabsf(u2 - f2) - 0.5f);
  float d3 = fabsf(fabsf(u3 - f3) - 0.5f);
  bool near = (d0 < 3e-5f) | (d1 < 3e-5f) | (d2 < 3e-5f) | (d3 < 3e-5f);
  if (__any(near)) {
    f0 = rintf(t0 / s); f1 = rintf(t1 / s);
    f2 = rintf(t2 / s); f3 = rintf(t3 / s);
  }
  k0 = fminf(fmaxf(f0, 0.f), 15.f);
  k1 = fminf(fmaxf(f1, 0.f), 15.f);
  k2 = fminf(fmaxf(f2, 0.f), 15.f);
  k3 = fminf(fmaxf(f3, 0.f), 15.f);
}

// 4 u8 -> 2 dwords of packed bf16
__device__ __forceinline__ void cvt2(unsigned int d, unsigned int &lo, unsigned int &hi) {
  float f0 = (float)(d & 0xffu);
  float f1 = (float)((d >> 8) & 0xffu);
  float f2 = (float)((d >> 16) & 0xffu);
  float f3 = (float)(d >> 24);
  lo = (__builtin_bit_cast(unsigned int, f0) >> 16) | (__builtin_bit_cast(unsigned int, f1) & 0xffff0000u);
  hi = (__builtin_bit_cast(unsigned int, f2) >> 16) | (__builtin_bit_cast(unsigned int, f3) & 0xffff0000u);
}

__device__ __forceinline__ float wmax16(float v) {
  #pragma unroll
  for (int s = 1; s < 16; s <<= 1) v = fmaxf(v, __shfl_xor(v, s));
  return v;
}
__device__ __forceinline__ float wmax64(float v) {
  #pragma unroll
  for (int s = 1; s < 64; s <<= 1) v = fmaxf(v, __shfl_xor(v, s));
  return v;
}

// ---------------- prep: quantize weights, fold BN constants ----------------
__global__ __launch_bounds__(64) void prep_kernel(PArgs P, char* __restrict__ ws) {
  int bi = blockIdx.x, l = threadIdx.x;
  float* wq1 = (float*)(ws + OFF_WQ1);
  float* r3f = (float*)(ws + OFF_R3F);
  f32x4* cst1 = (f32x4*)(ws + OFF_CST1);
  f32x4* cst2 = (f32x4*)(ws + OFF_CST2);
  f32x4* cst3 = (f32x4*)(ws + OFF_CST3);
  f32x4* cst4 = (f32x4*)(ws + OFF_CST4);
  unsigned short* r2 = (unsigned short*)(ws + OFF_R2BF);
  unsigned short* r4 = (unsigned short*)(ws + OFF_R4BF);
  unsigned short* r5 = (unsigned short*)(ws + OFF_R5BF);
  float2* cst5 = (float2*)(ws + OFF_CST5);

  if (bi < 128) {
    int c = bi;
    float w = (l < 9) ? P.dw1[c * 9 + l] : 0.f;
    float mx = wmax16(fabsf(w));
    float sq = fmaxf(mx / 7.0f, 1e-8f);
    if (l < 9) wq1[c * 12 + l] = clip7(rintf(w / sq)) * sq;
    if (l == 0) {
      float sc = P.g1[c] / sqrtf(P.v1[c] + EPSV);
      cst1[c] = f32x4{1.f, sc, P.m1[c], P.b1[c]};
    }
  } else if (bi < 256) {
    int o = bi - 128;
    float w0 = P.pw1[o * 128 + l], w1 = P.pw1[o * 128 + 64 + l];
    float mx = wmax64(fmaxf(fabsf(w0), fabsf(w1)));
    float sq = fmaxf(mx / 7.0f, 1e-8f);
    r2[o * 128 + l]      = f2bf(clip7(rintf(w0 / sq)));
    r2[o * 128 + 64 + l] = f2bf(clip7(rintf(w1 / sq)));
    if (l == 0) {
      float sc = P.g2[o] / sqrtf(P.v2[o] + EPSV);
      cst2[o] = f32x4{P.s1[0] * sq, sc, P.m2[o], P.b2[o]};
    }
  } else if (bi < 384) {
    int c = bi - 256;
    float w = (l < 9) ? P.dw2[c * 9 + l] : 0.f;
    float mx = wmax16(fabsf(w));
    float sq = fmaxf(mx / 7.0f, 1e-8f);
    if (l < 9) r3f[l * 128 + c] = clip7(rintf(w / sq));
    if (l == 0) {
      float sc = P.g3[c] / sqrtf(P.v3[c] + EPSV);
      cst3[c] = f32x4{P.s2[0] * sq, sc, P.m3[c], P.b3[c]};
    }
  } else if (bi < 512) {
    int o = bi - 384;
    float w0 = P.pw2[o * 128 + l], w1 = P.pw2[o * 128 + 64 + l];
    float mx = wmax64(fmaxf(fabsf(w0), fabsf(w1)));
    float sq = fmaxf(mx / 7.0f, 1e-8f);
    r4[o * 128 + l]      = f2bf(clip7(rintf(w0 / sq)));
    r4[o * 128 + 64 + l] = f2bf(clip7(rintf(w1 / sq)));
    if (l == 0) {
      float sc = P.g4[o] / sqrtf(P.v4[o] + EPSV);
      cst4[o] = f32x4{P.s3[0] * sq, sc, P.m4[o], P.b4[o]};
    }
  } else {
    int o = bi - 512;
    if (o < 19) {
      float w0 = P.clsw[o * 128 + l], w1 = P.clsw[o * 128 + 64 + l];
      float mx = wmax64(fmaxf(fabsf(w0), fabsf(w1)));
      float sq = fmaxf(mx / 7.0f, 1e-8f);
      r5[o * 128 + l]      = f2bf(clip7(rintf(w0 / sq)));
      r5[o * 128 + 64 + l] = f2bf(clip7(rintf(w1 / sq)));
      if (l == 0) {
        float A5 = P.s4[0] * sq;
        float bq = rintf(P.clsb[o] / A5) * A5;
        cst5[o] = make_float2(A5, bq);
      }
    } else {
      r5[o * 128 + l] = 0; r5[o * 128 + 64 + l] = 0;
      if (l == 0) cst5[o] = make_float2(0.f, 0.f);
    }
  }
}

// ---------------- dw-conv1 phase A: per-plane streaming, rolling 3-row window ----------------
__global__ __launch_bounds__(512) void dwA_kernel(const float* __restrict__ x,
                                                  char* __restrict__ ws,
                                                  const float* __restrict__ s1p) {
  int bid = blockIdx.x;
  int b = bid & 7, c = bid >> 3;              // XCD x owns image b=x
  int tid = threadIdx.x;
  int wq = tid & 63, wv = tid >> 6;
  int w0 = wq << 2;
  int h0 = wv << 4;
  const float* wp = (const float*)(ws + OFF_WQ1) + c * 12;
  float k0 = wp[0], k1 = wp[1], k2 = wp[2], k3 = wp[3], k4 = wp[4],
        k5 = wp[5], k6 = wp[6], k7 = wp[7], k8 = wp[8];
  f32x4 cs = ((const f32x4*)(ws + OFF_CST1))[c];
  float s_act = *s1p;
  float rs = 1.0f / s_act;
  const float* plane = x + (((size_t)((b << 7) | c)) << 15);
  unsigned char* oplane = (unsigned char*)(ws + OFF_BUFB) + (((size_t)((b << 7) | c)) << 15);

  f32x4 vm = {0.f, 0.f, 0.f, 0.f};
  if (h0 > 0) vm = *(const f32x4*)(plane + ((h0 - 1) << 8) + w0);
  f32x4 v0 = *(const f32x4*)(plane + (h0 << 8) + w0);
  f32x4 vp = *(const f32x4*)(plane + ((h0 + 1) << 8) + w0);
  float lm = __shfl_up(vm.w, 1), l0 = __shfl_up(v0.w, 1), lp = __shfl_up(vp.w, 1);
  float rm = __shfl_down(vm.x, 1), r0 = __shfl_down(v0.x, 1), rp = __shfl_down(vp.x, 1);
  if (wq == 0)  { lm = 0.f; l0 = 0.f; lp = 0.f; }
  if (wq == 63) { rm = 0.f; r0 = 0.f; rp = 0.f; }

  #pragma unroll 4
  for (int i = 0; i < 16; i++) {
    int h = h0 + i;
    float y0 = 0.f, y1 = 0.f, y2 = 0.f, y3 = 0.f;
    // row -1 (k0,k1,k2) then row 0 (k3,k4,k5) then row +1 (k6,k7,k8) — r1 order
    y0 = fmaf(lm,   k0, y0); y0 = fmaf(vm.x, k1, y0); y0 = fmaf(vm.y, k2, y0);
    y1 = fmaf(vm.x, k0, y1); y1 = fmaf(vm.y, k1, y1); y1 = fmaf(vm.z, k2, y1);
    y2 = fmaf(vm.y, k0, y2); y2 = fmaf(vm.z, k1, y2); y2 = fmaf(vm.w, k2, y2);
    y3 = fmaf(vm.z, k0, y3); y3 = fmaf(vm.w, k1, y3); y3 = fmaf(rm,   k2, y3);

    y0 = fmaf(l0,   k3, y0); y0 = fmaf(v0.x, k4, y0); y0 = fmaf(v0.y, k5, y0);
    y1 = fmaf(v0.x, k3, y1); y1 = fmaf(v0.y, k4, y1); y1 = fmaf(v0.z, k5, y1);
    y2 = fmaf(v0.y, k3, y2); y2 = fmaf(v0.z, k4, y2); y2 = fmaf(v0.w, k5, y2);
    y3 = fmaf(v0.z, k3, y3); y3 = fmaf(v0.w, k4, y3); y3 = fmaf(r0,   k5, y3);

    y0 = fmaf(lp,   k6, y0); y0 = fmaf(vp.x, k7, y0); y0 = fmaf(vp.y, k8, y0);
    y1 = fmaf(vp.x, k6, y1); y1 = fmaf(vp.y, k7, y1); y1 = fmaf(vp.z, k8, y1);
    y2 = fmaf(vp.y, k6, y2); y2 = fmaf(vp.z, k7, y2); y2 = fmaf(vp.w, k8, y2);
    y3 = fmaf(vp.z, k6, y3); y3 = fmaf(vp.w, k7, y3); y3 = fmaf(rp,   k8, y3);

    float q0, q1, q2, q3;
    qstep4(bnval(y0, cs), bnval(y1, cs), bnval(y2, cs), bnval(y3, cs),
           s_act, rs, q0, q1, q2, q3);
    unsigned int pk = (unsigned int)q0 | ((unsigned int)q1 << 8) |
                      ((unsigned int)q2 << 16) | ((unsigned int)q3 << 24);
    *(unsigned int*)(oplane + (h << 8) + w0) = pk;

    // shift window; load row h+2 for next iteration
    vm = v0; lm = l0; rm = r0;
    v0 = vp; l0 = lp; r0 = rp;
    f32x4 nv = {0.f, 0.f, 0.f, 0.f};
    if (i < 15 && h + 2 < 128) nv = *(const f32x4*)(plane + ((h + 2) << 8) + w0);
    vp = nv;
    float nl = __shfl_up(nv.w, 1), nr = __shfl_down(nv.x, 1);
    if (wq == 0)  nl = 0.f;
    if (wq == 63) nr = 0.f;
    lp = nl; rp = nr;
  }
}

// ---------------- pw1 from NCHW: staging does the transpose in-register ----------------
__global__ __launch_bounds__(256) void pwn_kernel(const unsigned char* __restrict__ in,
                                                  unsigned char* __restrict__ out,
                                                  const unsigned short* __restrict__ rbf,
                                                  const f32x4* __restrict__ cst,
                                                  const float* __restrict__ sp) {
  __shared__ unsigned char lds[32768];
  int tid = threadIdx.x;
  int bid = blockIdx.x;
  int sbid = ((bid & 7) << 8) | (bid >> 3);   // XCD x -> image x, rows sequential
  int p0 = sbid << 7;
  int b_img = p0 >> 15, loc0 = p0 & 32767;
  {
    int pb = tid & 7, cq = tid >> 3;
    int c4 = cq << 2;
    int kc = cq >> 3, lgr = (cq >> 1) & 3, hlf = cq & 1;
    const unsigned char* ib = in + (((size_t)(b_img << 7)) << 15) + loc0 + (pb << 4);
    u32x4 t0 = *(const u32x4*)(ib + ((size_t)(c4 + 0) << 15));
    u32x4 t1 = *(const u32x4*)(ib + ((size_t)(c4 + 1) << 15));
    u32x4 t2 = *(const u32x4*)(ib + ((size_t)(c4 + 2) << 15));
    u32x4 t3 = *(const u32x4*)(ib + ((size_t)(c4 + 3) << 15));
    int swz = (pb & 7) << 4;
    #pragma unroll
    for (int s = 0; s < 16; s++) {
      int wrd = s >> 2, sh8 = (s & 3) << 3;
      unsigned int chw = ((t0[wrd] >> sh8) & 0xffu)
                       | (((t1[wrd] >> sh8) & 0xffu) << 8)
                       | (((t2[wrd] >> sh8) & 0xffu) << 16)
                       | (((t3[wrd] >> sh8) & 0xffu) << 24);
      unsigned int lo, hi;
      cvt2(chw, lo, hi);
      int ad = ((((((pb << 2) + kc) << 6) | s | (lgr << 4)) << 4) + (hlf << 3)) ^ swz;
      *(u32x2*)(lds + ad) = u32x2{lo, hi};
    }
  }
  __syncthreads();
  int l = tid & 63, wv = tid >> 6;
  int ob = wv << 5;                          // wave owns 32 output channels
  bf16x8 af[2][4];
  #pragma unroll
  for (int ot = 0; ot < 2; ot++)
    #pragma unroll
    for (int kc = 0; kc < 4; kc++) {
      int o = ob + (ot << 4) + (l & 15);
      int k = (kc << 5) + ((l >> 4) << 3);
      af[ot][kc] = *(const bf16x8*)(rbf + o * 128 + k);
    }
  f32x4 acc[2][8];
  #pragma unroll
  for (int ot = 0; ot < 2; ot++)
    #pragma unroll
    for (int pt = 0; pt < 8; pt++) acc[ot][pt] = f32x4{0.f, 0.f, 0.f, 0.f};
  #pragma unroll
  for (int kc = 0; kc < 4; kc++) {
    bf16x8 bb[8];
    #pragma unroll
    for (int pt = 0; pt < 8; pt++)
      bb[pt] = *(const bf16x8*)(lds + (((((((pt << 2) + kc) << 6)) + l) << 4) ^ ((pt & 7) << 4)));
    #pragma unroll
    for (int ot = 0; ot < 2; ot++)
      #pragma unroll
      for (int pt = 0; pt < 8; pt++)
        acc[ot][pt] = __builtin_amdgcn_mfma_f32_16x16x32_bf16(af[ot][kc], bb[pt], acc[ot][pt], 0, 0, 0);
  }
  float s_act = *sp;
  float rs = 1.0f / s_act;
  #pragma unroll
  for (int ot = 0; ot < 2; ot++) {
    int o0 = ob + (ot << 4) + ((l >> 4) << 2);
    f32x4 c0 = cst[o0], c1 = cst[o0 + 1], c2 = cst[o0 + 2], c3 = cst[o0 + 3];
    #pragma unroll
    for (int pt = 0; pt < 8; pt++) {
      int p = p0 + (pt << 4) + (l & 15);
      f32x4 a = acc[ot][pt];
      float q0, q1, q2, q3;
      qstep4(bnval(a.x, c0), bnval(a.y, c1), bnval(a.z, c2), bnval(a.w, c3),
             s_act, rs, q0, q1, q2, q3);
      unsigned int pk = (unsigned int)q0 | ((unsigned int)q1 << 8) |
                        ((unsigned int)q2 << 16) | ((unsigned int)q3 << 24);
      *(unsigned int*)(out + (size_t)p * 128 + o0) = pk;
    }
  }
}

// ---------------- fused dw2 + BN3 + qrelu + pw2 + BN4 + qrelu + classifier ----------------
// r13 structure (128-pos blocks, 64KB LDS, no phase2->3 barrier, XCD swizzle) with
// phase-1 u8->f32 conversion hoisted per row (r-outer loop; per-output fmaf order
// unchanged -> bit-identical).
__global__ __launch_bounds__(256) void dw2pwcls_kernel(const unsigned char* __restrict__ in,
                                                       float* __restrict__ out,
                                                       const char* __restrict__ ws,
                                                       const unsigned short* __restrict__ rbf,
                                                       const f32x4* __restrict__ cst,
                                                       const float* __restrict__ s3p,
                                                       const float* __restrict__ s4p,
                                                       const unsigned short* __restrict__ r5,
                                                       const float2* __restrict__ cst5) {
  __shared__ unsigned char lds[65536];
  int tid = threadIdx.x;
  int bid = blockIdx.x;
  int sbid = ((bid & 7) << 8) | (bid >> 3);   // XCD x -> image x, rows sequential
  int p0 = sbid << 7;                         // 128 consecutive positions, single h row
  // ---- phase 1: dw2 sliding window -> bf16 fragments (swizzled) ----
  {
    int cq = tid & 31, pg = tid >> 5;
    int c4 = cq << 2;
    const float* r3f = (const float*)(ws + OFF_R3F);
    float wk[9][4];
    #pragma unroll
    for (int t = 0; t < 9; t++) {
      wk[t][0] = r3f[t * 128 + c4];     wk[t][1] = r3f[t * 128 + c4 + 1];
      wk[t][2] = r3f[t * 128 + c4 + 2]; wk[t][3] = r3f[t * 128 + c4 + 3];
    }
    const f32x4* cst3 = (const f32x4*)(ws + OFF_CST3);
    f32x4 cs0 = cst3[c4], cs1 = cst3[c4 + 1], cs2 = cst3[c4 + 2], cs3 = cst3[c4 + 3];
    float s_act3 = *s3p;
    float rs3 = 1.0f / s_act3;
    int kc = c4 >> 5, hi = (c4 >> 3) & 3, hlf = (c4 >> 2) & 1;
    int g = hi | ((kc & 1) << 2);
    int hh = (p0 >> 8) & 127;          // block-uniform row index
    #pragma unroll 2
    for (int ps = 0; ps < 4; ps++) {
      int pbase = p0 + (ps << 5) + (pg << 2);   // 4 consecutive positions
      int wbase = pbase & 255;
      float aj[4][4];
      #pragma unroll
      for (int j = 0; j < 4; j++) {
        aj[j][0] = 0.f; aj[j][1] = 0.f; aj[j][2] = 0.f; aj[j][3] = 0.f;
      }
      #pragma unroll
      for (int r = 0; r < 3; r++) {
        int gh = hh + r - 1;
        unsigned int vv[6];
        if (gh >= 0 && gh <= 127) {    // uniform branch
          const unsigned char* rp = in + (size_t)(pbase + (r - 1) * 256) * 128 + c4;
          vv[0] = (wbase > 0)   ? *(const unsigned int*)(rp - 128) : 0u;
          vv[1] = *(const unsigned int*)(rp);
          vv[2] = *(const unsigned int*)(rp + 128);
          vv[3] = *(const unsigned int*)(rp + 256);
          vv[4] = *(const unsigned int*)(rp + 384);
          vv[5] = (wbase < 252) ? *(const unsigned int*)(rp + 512) : 0u;
        } else {
          vv[0] = 0u; vv[1] = 0u; vv[2] = 0u; vv[3] = 0u; vv[4] = 0u; vv[5] = 0u;
        }
        // hoisted conversion: 24 floats per row, reused by all j
        float xf[6][4];
        #pragma unroll
        for (int i = 0; i < 6; i++) {
          xf[i][0] = (float)(vv[i] & 0xffu);
          xf[i][1] = (float)((vv[i] >> 8) & 0xffu);
          xf[i][2] = (float)((vv[i] >> 16) & 0xffu);
          xf[i][3] = (float)(vv[i] >> 24);
        }
        #pragma unroll
        for (int j = 0; j < 4; j++) {
          #pragma unroll
          for (int dwi = 0; dwi < 3; dwi++) {
            int t = r * 3 + dwi;
            aj[j][0] = fmaf(xf[j + dwi][0], wk[t][0], aj[j][0]);
            aj[j][1] = fmaf(xf[j + dwi][1], wk[t][1], aj[j][1]);
            aj[j][2] = fmaf(xf[j + dwi][2], wk[t][2], aj[j][2]);
            aj[j][3] = fmaf(xf[j + dwi][3], wk[t][3], aj[j][3]);
          }
        }
      }
      #pragma unroll
      for (int j = 0; j < 4; j++) {
        float k0f, k1f, k2f, k3f;
        qstep4(bnval(aj[j][0], cs0), bnval(aj[j][1], cs1),
               bnval(aj[j][2], cs2), bnval(aj[j][3], cs3),
               s_act3, rs3, k0f, k1f, k2f, k3f);
        // bf16(small int float) == cvt2-of-u8 path exactly
        unsigned int wlo = (__builtin_bit_cast(unsigned int, k0f) >> 16) |
                           (__builtin_bit_cast(unsigned int, k1f) & 0xffff0000u);
        unsigned int whi = (__builtin_bit_cast(unsigned int, k2f) >> 16) |
                           (__builtin_bit_cast(unsigned int, k3f) & 0xffff0000u);
        int p_local = (ps << 5) + (pg << 2) + j;
        int pt = p_local >> 4, pl = p_local & 15;
        int slot = (pl ^ g) | (hi << 4);
        int ad = (((((pt << 2) + kc) << 6) | slot) << 4) + (hlf << 3);
        *(u32x2*)(lds + ad) = u32x2{wlo, whi};
      }
    }
  }
  __syncthreads();
  // ---- phase 2: pw2 MFMA (reads swizzled fragments) ----
  int l = tid & 63, wv = tid >> 6;
  int ob = wv << 5;
  bf16x8 af[2][4];
  #pragma unroll
  for (int ot = 0; ot < 2; ot++)
    #pragma unroll
    for (int kc = 0; kc < 4; kc++) {
      int o = ob + (ot << 4) + (l & 15);
      int k = (kc << 5) + ((l >> 4) << 3);
      af[ot][kc] = *(const bf16x8*)(rbf + o * 128 + k);
    }
  f32x4 acc[2][8];
  #pragma unroll
  for (int ot = 0; ot < 2; ot++)
    #pragma unroll
    for (int pt = 0; pt < 8; pt++) acc[ot][pt] = f32x4{0.f, 0.f, 0.f, 0.f};
  #pragma unroll
  for (int kc = 0; kc < 4; kc++) {
    int gg = (l >> 4) | ((kc & 1) << 2);
    bf16x8 bb[8];
    #pragma unroll
    for (int pt = 0; pt < 8; pt++)
      bb[pt] = *(const bf16x8*)(lds + ((((((pt << 2) + kc) << 6)) | (l ^ gg)) << 4));
    #pragma unroll
    for (int ot = 0; ot < 2; ot++)
      #pragma unroll
      for (int pt = 0; pt < 8; pt++)
        acc[ot][pt] = __builtin_amdgcn_mfma_f32_16x16x32_bf16(af[ot][kc], bb[pt], acc[ot][pt], 0, 0, 0);
  }
  float s_act4 = *s4p;
  float rs4 = 1.0f / s_act4;
  // ---- phase 3: BN4+qrelu -> k4 bf16 fragments at +32K (disjoint; no barrier) ----
  {
    int hsel = (l >> 4) & 1;
    #pragma unroll
    for (int ot = 0; ot < 2; ot++) {
      int o0 = ob + (ot << 4) + ((l >> 4) << 2);
      f32x4 c0 = cst[o0], c1 = cst[o0 + 1], c2 = cst[o0 + 2], c3 = cst[o0 + 3];
      int hi = (ot << 1) + ((l >> 4) >> 1);
      int lfrag = (l & 15) | (hi << 4);
      #pragma unroll
      for (int pt = 0; pt < 8; pt++) {
        f32x4 a = acc[ot][pt];
        float k0f, k1f, k2f, k3f;
        qstep4(bnval(a.x, c0), bnval(a.y, c1), bnval(a.z, c2), bnval(a.w, c3),
               s_act4, rs4, k0f, k1f, k2f, k3f);
        unsigned int w0 = (__builtin_bit_cast(unsigned int, k0f) >> 16) |
                          (__builtin_bit_cast(unsigned int, k1f) & 0xffff0000u);
        unsigned int w1 = (__builtin_bit_cast(unsigned int, k2f) >> 16) |
                          (__builtin_bit_cast(unsigned int, k3f) & 0xffff0000u);
        int ad = 32768 + ((((((pt << 2) + wv) << 6) | lfrag) << 4) + (hsel << 3));
        *(u32x2*)(lds + ad) = u32x2{w0, w1};
      }
    }
  }
  __syncthreads();
  // ---- phase 4: classifier MFMA (k4 fragments at +32K) ----
  int pt0 = wv << 1;
  bf16x8 af5[2][4];
  #pragma unroll
  for (int ot = 0; ot < 2; ot++)
    #pragma unroll
    for (int kc = 0; kc < 4; kc++) {
      int o = (ot << 4) + (l & 15);
      int k = (kc << 5) + ((l >> 4) << 3);
      af5[ot][kc] = *(const bf16x8*)(r5 + o * 128 + k);
    }
  f32x4 a5[2][2] = {{{0,0,0,0},{0,0,0,0}},{{0,0,0,0},{0,0,0,0}}};
  #pragma unroll
  for (int kc = 0; kc < 4; kc++) {
    bf16x8 b0 = *(const bf16x8*)(lds + 32768 + ((((((pt0    ) << 2) + kc) << 6) + l) << 4));
    bf16x8 b1 = *(const bf16x8*)(lds + 32768 + ((((((pt0 + 1) << 2) + kc) << 6) + l) << 4));
    #pragma unroll
    for (int ot = 0; ot < 2; ot++) {
      a5[ot][0] = __builtin_amdgcn_mfma_f32_16x16x32_bf16(af5[ot][kc], b0, a5[ot][0], 0, 0, 0);
      a5[ot][1] = __builtin_amdgcn_mfma_f32_16x16x32_bf16(af5[ot][kc], b1, a5[ot][1], 0, 0, 0);
    }
  }
  #pragma unroll
  for (int ptl = 0; ptl < 2; ptl++) {
    int p = p0 + ((pt0 + ptl) << 4) + (l & 15);
    int bb = p >> 15, hw = p & 32767;
    float* ob2 = out + (((size_t)bb * 19) << 15) + hw;
    #pragma unroll
    for (int ot = 0; ot < 2; ot++) {
      int obase = (ot << 4) + ((l >> 4) << 2);
      f32x4 a = a5[ot][ptl];
      #pragma unroll
      for (int i = 0; i < 4; i++) {
        int o = obase + i;
        if (o < 19) {
          float2 c5 = cst5[o];
          ob2[(size_t)o << 15] = fmaf(a[i], c5.x, c5.y);
        }
      }
    }
  }
}

// ---------------- launch ----------------
extern "C" void kernel_launch(void* const* d_in, const int* in_sizes, int n_in,
                              void* d_out, int out_size, void* d_ws, size_t ws_size,
                              hipStream_t stream) {
  (void)in_sizes; (void)n_in; (void)out_size; (void)ws_size;
  char* ws = (char*)d_ws;
  PArgs P;
  P.dw1  = (const float*)d_in[1];
  P.pw1  = (const float*)d_in[2];
  P.dw2  = (const float*)d_in[3];
  P.pw2  = (const float*)d_in[4];
  P.clsw = (const float*)d_in[5];
  P.clsb = (const float*)d_in[6];
  P.g1 = (const float*)d_in[7];  P.b1 = (const float*)d_in[8];
  P.m1 = (const float*)d_in[9];  P.v1 = (const float*)d_in[10];
  P.g2 = (const float*)d_in[11]; P.b2 = (const float*)d_in[12];
  P.m2 = (const float*)d_in[13]; P.v2 = (const float*)d_in[14];
  P.g3 = (const float*)d_in[15]; P.b3 = (const float*)d_in[16];
  P.m3 = (const float*)d_in[17]; P.v3 = (const float*)d_in[18];
  P.g4 = (const float*)d_in[19]; P.b4 = (const float*)d_in[20];
  P.m4 = (const float*)d_in[21]; P.v4 = (const float*)d_in[22];
  P.s1 = (const float*)d_in[23]; P.s2 = (const float*)d_in[24];
  P.s3 = (const float*)d_in[25]; P.s4 = (const float*)d_in[26];

  const float* x = (const float*)d_in[0];
  unsigned char* bufA = (unsigned char*)(ws + OFF_BUFA);
  unsigned char* bufB = (unsigned char*)(ws + OFF_BUFB);

  prep_kernel<<<544, 64, 0, stream>>>(P, ws);
  dwA_kernel<<<1024, 512, 0, stream>>>(x, ws, P.s1);                       // x -> k1 NCHW u8 (B)
  pwn_kernel<<<2048, 256, 0, stream>>>(bufB, bufA,
      (const unsigned short*)(ws + OFF_R2BF), (const f32x4*)(ws + OFF_CST2), P.s2);  // k1 NCHW -> k2 NHWC (A)
  dw2pwcls_kernel<<<2048, 256, 0, stream>>>(bufA, (float*)d_out, ws,
      (const unsigned short*)(ws + OFF_R4BF), (const f32x4*)(ws + OFF_CST4),
      P.s3, P.s4,
      (const unsigned short*)(ws + OFF_R5BF), (const float2*)(ws + OFF_CST5));       // k2 -> out
}